// Round 17
// baseline (493.835 us; speedup 1.0000x reference)
//
#include <hip/hip_runtime.h>

// f32-rounded scalars (jax weak-scalar semantics)
#define ALPHA_F ((float)0.8187307530779818)
#define BETA_F  ((float)0.9048374180359595)

// V9: pure-register SNN. lane = (pixel-half, channel): spike exchange via
// __ballot (no LDS, no barriers in the t-loop); weights/D-column/bias per-lane
// VGPRs (D built once via readlane); x-window via 18 t-invariant clamped
// offsets + uniform plane base; zero-pad via AND-masks (exact +0.0).
// V8 was LDS-issue-bound (~80+ uniform ds_reads/thread/t); V9 has ZERO.
// All arithmetic chains bit-identical to the passing V2..V8 (absmax 0.0).

// raw weight index for chain position (kt segment, jj=(kh*3+kw)*2+ci)
#define RAWIDX(KT, JJ) ((((JJ)&1) * 27) + ((KT) * 9) + ((((JJ)>>1) / 3) * 3) + (((JJ)>>1) % 3))

__global__ __launch_bounds__(512, 2) void snn_v9(
    const float* __restrict__ x, const float* __restrict__ wq,
    const float* __restrict__ bvec, float* __restrict__ out)
{
    const int tid  = threadIdx.x;
    const int lane = tid & 63;
    const int wv   = tid >> 6;       // wave 0..7 -> w-pair
    const int p    = lane >> 5;      // pixel half (A/B)
    const int c    = lane & 31;      // channel (bit position in ballot!)

    // XCD-chunked swizzle: 2048 blocks, 256/XCD -> each XCD owns one b
    const int orig = blockIdx.x;
    const int wgid = (orig & 7) * 256 + (orig >> 3);
    const int b  = wgid >> 8;
    const int h  = (wgid >> 2) & 63;
    const int wc = wgid & 3;
    const int w  = wc * 16 + wv * 2 + p;

    // ---- per-lane raw weights (own channel's row) ----
    float wr[54];
    #pragma unroll
    for (int k = 0; k < 54; ++k) wr[k] = wq[c * 54 + k];

    // ---- D column D[cp][c]: sequential FMA chain k ascending (== V2 gram),
    //      row cp broadcast from lane cp via readlane ----
    float Dc[32];
    #pragma unroll
    for (int cp = 0; cp < 32; ++cp) {
        float s = 0.f;
        #pragma unroll
        for (int k = 0; k < 54; ++k) {
            float wcp = __int_as_float(__builtin_amdgcn_readlane(__float_as_int(wr[k]), cp));
            s = fmaf(wcp, wr[k], s);
        }
        Dc[cp] = s;
    }

    // ---- norm (sequential mul-add ascending), IEEE divide, bias ----
    float nrm = 0.f;
    #pragma unroll
    for (int k = 0; k < 54; ++k) nrm = __fadd_rn(nrm, __fmul_rn(wr[k], wr[k]));
    const float inv_r  = 1.0f / __fadd_rn(nrm, 1e-8f);
    const float bias_r = bvec[c];

    // ---- 18 t-invariant clamped element offsets + validity pack ----
    int offs[18];
    int selpack = 0;
    #pragma unroll
    for (int ci = 0; ci < 2; ++ci) {
        #pragma unroll
        for (int kh = 0; kh < 3; ++kh) {
            int hh = h + kh - 1;
            bool hok = (unsigned)hh < 64u;
            int base = ci * 262144 + (hok ? hh : 0) * 64;
            int j0 = (kh * 3 + 0) * 2 + ci;
            int j1 = (kh * 3 + 1) * 2 + ci;
            int j2 = (kh * 3 + 2) * 2 + ci;
            offs[j0] = base + ((w > 0) ? (w - 1) : 0);
            offs[j1] = base + w;
            offs[j2] = base + ((w < 63) ? (w + 1) : 63);
            selpack |= ((hok && w > 0)  ? 1 : 0) << j0;
            selpack |= ( hok            ? 1 : 0) << j1;
            selpack |= ((hok && w < 63) ? 1 : 0) << j2;
        }
    }

    const size_t xb = (size_t)b * 524288;
    float* op = out + (size_t)b * 8388608 + (size_t)c * 262144
              + (size_t)h * 64 + (size_t)w;

    // ---- gather plane into xv with exact +0.0 padding (AND-mask) ----
    float xv[18];
    #define GATHER_XV(PLANE_T)                                                 \
    {                                                                          \
        const float* xt = x + xb + (size_t)(PLANE_T) * 4096;                   \
        _Pragma("unroll")                                                      \
        for (int j = 0; j < 18; ++j) {                                         \
            float ld = xt[offs[j]];                                            \
            int m = (selpack << (31 - j)) >> 31;   /* 0 or -1 */               \
            xv[j] = __int_as_float(__float_as_int(ld) & m);                    \
        }                                                                      \
    }

    // ---- prologue: S1 = kt0-chain(plane0), S2 = kt1-chain(plane0) ----
    float S1, S2, mem = 0.f, syn = 0.f;
    bool spk = false;
    GATHER_XV(0);
    {
        float a = 0.f, s = 0.f;
        #pragma unroll
        for (int jj = 0; jj < 18; ++jj) a = fmaf(xv[jj], wr[RAWIDX(1, jj)], a);
        S2 = a;
        #pragma unroll
        for (int jj = 0; jj < 18; ++jj) s = fmaf(xv[jj], wr[RAWIDX(0, jj)], s);
        S1 = s;
    }

    for (int t = 0; t < 64; ++t) {
        // ---- spike mask via ballot (bit c = channel c of each pixel half) ----
        unsigned long long bal = __ballot(spk);
        unsigned mask = (unsigned)(p ? (bal >> 32) : bal);

        // ---- rst: fmaf(s, D, rst), cp ascending, from registers (bit-exact) ----
        float rst = 0.f;
        if (bal) {
            #pragma unroll
            for (int cp = 0; cp < 32; ++cp) {
                float s = (float)((mask >> cp) & 1u);
                rst = fmaf(s, Dc[cp], rst);
            }
        }

        // ---- mem update (OLD syn), spike, store ----
        float bm = __fmul_rn(BETA_F, mem);
        float bs = __fadd_rn(bm, syn);
        mem = __fsub_rn(bs, rst);
        float mthr = __fsub_rn(__fmul_rn(mem, inv_r), bias_r);
        spk = mthr > 0.f;
        op[(size_t)t * 4096] = spk ? 1.0f : 0.0f;

        // ---- gather plane t+1 (zeros past end: exact padding) ----
        if (t < 63) {
            GATHER_XV(t + 1);
        } else {
            #pragma unroll
            for (int j = 0; j < 18; ++j) xv[j] = 0.f;
        }

        // ---- conv: acc = S2 + kt2-chain; advance prefixes (== V7/V8) ----
        float acc = S2;
        #pragma unroll
        for (int jj = 0; jj < 18; ++jj) acc = fmaf(xv[jj], wr[RAWIDX(2, jj)], acc);
        float nS2 = S1;
        #pragma unroll
        for (int jj = 0; jj < 18; ++jj) nS2 = fmaf(xv[jj], wr[RAWIDX(1, jj)], nS2);
        S2 = nS2;
        float nS1 = 0.f;
        #pragma unroll
        for (int jj = 0; jj < 18; ++jj) nS1 = fmaf(xv[jj], wr[RAWIDX(0, jj)], nS1);
        S1 = nS1;

        // ---- syn update: ALPHA*syn (f32), + conv (f32) ----
        syn = __fadd_rn(__fmul_rn(ALPHA_F, syn), acc);
    }
    #undef GATHER_XV
}

extern "C" void kernel_launch(void* const* d_in, const int* in_sizes, int n_in,
                              void* d_out, int out_size, void* d_ws, size_t ws_size,
                              hipStream_t stream) {
    const float* x  = (const float*)d_in[0];
    const float* wq = (const float*)d_in[1];
    const float* bv = (const float*)d_in[2];
    for (int i = 0; i < n_in; ++i) {
        int sz = in_sizes[i];
        if (sz == 8 * 2 * 64 * 64 * 64) x  = (const float*)d_in[i];
        else if (sz == 32 * 2 * 27)     wq = (const float*)d_in[i];
        else if (sz == 32)              bv = (const float*)d_in[i];
    }
    float* out = (float*)d_out;
    snn_v9<<<2048, 512, 0, stream>>>(x, wq, bv, out);
}